// Round 1
// baseline (629.109 us; speedup 1.0000x reference)
//
#include <hip/hip_runtime.h>
#include <math.h>

#define N_ENT 100000
#define KNBR 64
#define DHALF 500
#define TWO_D 1000
#define ATTN_DIM 128
#define ETA_MAX 0.5f

// ---------------------------------------------------------------------------
// Kernel A: per-anchor attention-score vector
//   M[b, :] = (Wk^T (Wq @ e_i)) / sqrt(ATTN)
// Folding Wk^T into the query removes the [B,K,ATTN] projection (16.8 GFLOP
// -> 0.52 GFLOP). 8 anchors per block to amortize Wq/Wk reads (L2 traffic
// 1 MB/block * 128 blocks = 128 MB L2, ~4 us).
// ---------------------------------------------------------------------------
__global__ __launch_bounds__(256) void precompute_m(
    const int* __restrict__ anchor_ids,
    const float* __restrict__ E,
    const float* __restrict__ Wq,
    const float* __restrict__ Wk,
    float* __restrict__ M, int B)
{
    __shared__ float e_lds[8][TWO_D];     // 32 KB
    __shared__ float qp[2][8][ATTN_DIM];  // 8 KB (two half-d partials)
    __shared__ float q_lds[8][ATTN_DIM];  // 4 KB
    const int t  = threadIdx.x;
    const int b0 = blockIdx.x * 8;

    // stage 8 anchor embeddings (rows are 4000 B, 16B-aligned -> float4 ok)
    for (int j = 0; j < 8; ++j) {
        int bb = b0 + j;
        int row = (bb < B) ? anchor_ids[bb] : 0;
        if (t < 250) {
            const float4* src = (const float4*)(E + (size_t)row * TWO_D);
            float4 v = src[t];
            e_lds[j][4 * t + 0] = v.x;
            e_lds[j][4 * t + 1] = v.y;
            e_lds[j][4 * t + 2] = v.z;
            e_lds[j][4 * t + 3] = v.w;
        }
    }
    __syncthreads();

    // GEMM1: q[j][a] = sum_d e[j][d] * Wq[a][d]; split d into two halves
    {
        const int a = t & 127;
        const int h = t >> 7;
        float acc[8] = {0.f, 0.f, 0.f, 0.f, 0.f, 0.f, 0.f, 0.f};
        const float* wrow = Wq + (size_t)a * TWO_D + h * DHALF;
        for (int d = 0; d < DHALF; ++d) {
            float w = wrow[d];
            int dd = h * DHALF + d;
#pragma unroll
            for (int j = 0; j < 8; ++j) acc[j] += w * e_lds[j][dd];
        }
#pragma unroll
        for (int j = 0; j < 8; ++j) qp[h][j][a] = acc[j];
    }
    __syncthreads();
    for (int idx = t; idx < 8 * ATTN_DIM; idx += 256) {
        ((float*)q_lds)[idx] = ((float*)qp)[idx] + ((float*)qp)[8 * ATTN_DIM + idx];
    }
    __syncthreads();

    // GEMM2: m[j][d] = sum_a q[j][a] * Wk[a][d]; thread t owns d = t + 256c
    const float inv_scale = 0.0883883476483184f;  // 1/sqrt(128)
    float acc2[4][8];
#pragma unroll
    for (int c = 0; c < 4; ++c)
#pragma unroll
        for (int j = 0; j < 8; ++j) acc2[c][j] = 0.f;

    for (int a = 0; a < ATTN_DIM; ++a) {
        const float* wkrow = Wk + (size_t)a * TWO_D;
        float wk[4];
#pragma unroll
        for (int c = 0; c < 4; ++c) {
            int d = t + 256 * c;
            wk[c] = (d < TWO_D) ? wkrow[d] : 0.f;  // coalesced
        }
#pragma unroll
        for (int j = 0; j < 8; ++j) {
            float qv = q_lds[j][a];  // broadcast
#pragma unroll
            for (int c = 0; c < 4; ++c) acc2[c][j] += qv * wk[c];
        }
    }
#pragma unroll
    for (int c = 0; c < 4; ++c) {
        int d = t + 256 * c;
        if (d < TWO_D) {
#pragma unroll
            for (int j = 0; j < 8; ++j) {
                int bb = b0 + j;
                if (bb < B) M[(size_t)bb * TWO_D + d] = acc2[c][j] * inv_scale;
            }
        }
    }
}

// ---------------------------------------------------------------------------
// Kernel B: one block per anchor. Single pass over neighbors with max-free
// online softmax (logits are O(0.1) by construction -> exp() is safe without
// max subtraction; masked lanes contribute exactly 0, matching exp(-10000)).
// Wave w handles neighbors w, w+4, ... : wave-internal shfl reduction for the
// logit dot, per-lane accumulation of sum_k p_k * hat_k over its 8 complex
// dims. Final 4-wave merge through 16 KB LDS. Neighbor embeddings are read
// exactly once (262 MB gather total -> the HBM floor).
// ---------------------------------------------------------------------------
__global__ __launch_bounds__(256) void refine(
    const int* __restrict__ anchor_ids,
    const int* __restrict__ nbr_ent,
    const int* __restrict__ nbr_rel,
    const int* __restrict__ nbr_dir,
    const int* __restrict__ nbr_mask,
    const float* __restrict__ freq,
    const float* __restrict__ E,
    const float* __restrict__ P,
    const float* __restrict__ a_param,
    const float* __restrict__ eta_raw_p,
    const float* __restrict__ w_raw_p,
    const float* __restrict__ b_p,
    const float* __restrict__ rel_bias,
    const float* __restrict__ dir_bias,
    const float* __restrict__ M,
    float* __restrict__ out)
{
    __shared__ float m_lds[TWO_D];     // 4 KB
    __shared__ float accm[4][TWO_D];   // 16 KB merge buffer
    __shared__ float sum_s[4];
    __shared__ int ent_s[KNBR], rel_s[KNBR], dir_s[KNBR], msk_s[KNBR];

    const int t = threadIdx.x;
    const int bid = blockIdx.x;
    const int anchor = anchor_ids[bid];

    for (int idx = t; idx < TWO_D; idx += 256)
        m_lds[idx] = M[(size_t)bid * TWO_D + idx];
    if (t < KNBR) {
        size_t off = (size_t)anchor * KNBR + t;
        ent_s[t] = nbr_ent[off];
        rel_s[t] = nbr_rel[off];
        dir_s[t] = nbr_dir[off];
        msk_s[t] = nbr_mask[off];
    }
    __syncthreads();

    const int lane = t & 63;
    const int wid = t >> 6;

    // lane-local slice of m (dims d = lane + 64*i)
    float mre[8], mim[8];
#pragma unroll
    for (int i = 0; i < 8; ++i) {
        int d = lane + 64 * i;
        mre[i] = (d < DHALF) ? m_lds[d] : 0.f;
        mim[i] = (d < DHALF) ? m_lds[DHALF + d] : 0.f;
    }

    float accre[8], accim[8];
#pragma unroll
    for (int i = 0; i < 8; ++i) { accre[i] = 0.f; accim[i] = 0.f; }
    float wsum = 0.f;
    const float db0 = dir_bias[0];
    const float db1 = dir_bias[1];

    for (int k = wid; k < KNBR; k += 4) {
        if (!msk_s[k]) continue;  // wave-uniform branch
        const int ent = ent_s[k];
        const int rel = rel_s[k];
        const int dirf = dir_s[k];
        const float* erow = E + (size_t)ent * TWO_D;
        const float* prow = P + (size_t)rel * DHALF;

        float hre[8], him[8];
        float dot = 0.f;
#pragma unroll
        for (int i = 0; i < 8; ++i) {
            int d = lane + 64 * i;
            if (d < DHALF) {
                float re = erow[d];
                float im = erow[DHALF + d];
                float ph = prow[d];
                float s, c;
                __sincosf(ph, &s, &c);
                if (dirf) s = -s;  // RotatE conjugate for reverse edges
                hre[i] = re * c - im * s;
                him[i] = re * s + im * c;
                dot += mre[i] * hre[i] + mim[i] * him[i];
            } else {
                hre[i] = 0.f;
                him[i] = 0.f;
            }
        }
        // 64-lane butterfly: every lane gets the full dot
        dot += __shfl_xor(dot, 32);
        dot += __shfl_xor(dot, 16);
        dot += __shfl_xor(dot, 8);
        dot += __shfl_xor(dot, 4);
        dot += __shfl_xor(dot, 2);
        dot += __shfl_xor(dot, 1);

        float logit = dot + rel_bias[rel] + (dirf ? db1 : db0);
        float p = __expf(logit);  // |logit| ~ 0.2 -> no max needed
        wsum += p;
#pragma unroll
        for (int i = 0; i < 8; ++i) {
            accre[i] += p * hre[i];
            accim[i] += p * him[i];
        }
    }

    if (lane == 0) sum_s[wid] = wsum;
#pragma unroll
    for (int i = 0; i < 8; ++i) {
        int d = lane + 64 * i;
        if (d < DHALF) {
            accm[wid][d] = accre[i];
            accm[wid][DHALF + d] = accim[i];
        }
    }
    __syncthreads();

    const float S = sum_s[0] + sum_s[1] + sum_s[2] + sum_s[3];
    const float invS = (S > 0.f) ? 1.f / S : 0.f;
    float eta = 0.f;
    if (S > 0.f) {  // has_nbr
        float logf_ = log1pf(freq[anchor]);
        float wv = log1pf(__expf(w_raw_p[0]));  // softplus(w_raw)
        float x = eta_raw_p[0] - wv * logf_ + b_p[0];
        eta = ETA_MAX / (1.f + __expf(-x));
    }

    const float* eirow = E + (size_t)anchor * TWO_D;
#pragma unroll
    for (int c = 0; c < 4; ++c) {
        int dd = t + 256 * c;
        if (dd < TWO_D) {
            float delta = (accm[0][dd] + accm[1][dd] + accm[2][dd] + accm[3][dd]) * invS;
            float ei = eirow[dd];
            float ap = a_param[(dd < DHALF) ? dd : dd - DHALF];
            // S==0: eta=0 -> out = e_i (matches reference's delta=e_i path)
            out[(size_t)bid * TWO_D + dd] = ei + eta * (ap * delta - ei);
        }
    }
}

extern "C" void kernel_launch(void* const* d_in, const int* in_sizes, int n_in,
                              void* d_out, int out_size, void* d_ws, size_t ws_size,
                              hipStream_t stream)
{
    const int*   anchor_ids = (const int*)d_in[0];
    const int*   nbr_ent    = (const int*)d_in[1];
    const int*   nbr_rel    = (const int*)d_in[2];
    const int*   nbr_dir    = (const int*)d_in[3];   // bool -> int32 per harness
    const int*   nbr_mask   = (const int*)d_in[4];   // bool -> int32 per harness
    const float* freq       = (const float*)d_in[5];
    const float* E          = (const float*)d_in[6];
    const float* P          = (const float*)d_in[7];
    const float* a_param    = (const float*)d_in[8];
    const float* eta_raw    = (const float*)d_in[9];
    const float* w_raw      = (const float*)d_in[10];
    const float* b_scalar   = (const float*)d_in[11];
    const float* Wq         = (const float*)d_in[12];
    const float* Wk         = (const float*)d_in[13];
    const float* rel_bias   = (const float*)d_in[14];
    const float* dir_bias   = (const float*)d_in[15];
    float* out = (float*)d_out;

    const int B = in_sizes[0];
    float* M = (float*)d_ws;  // B * 1000 floats = 4 MB scratch

    precompute_m<<<(B + 7) / 8, 256, 0, stream>>>(anchor_ids, E, Wq, Wk, M, B);
    refine<<<B, 256, 0, stream>>>(anchor_ids, nbr_ent, nbr_rel, nbr_dir, nbr_mask,
                                  freq, E, P, a_param, eta_raw, w_raw, b_scalar,
                                  rel_bias, dir_bias, M, out);
}